// Round 1
// baseline (1337.946 us; speedup 1.0000x reference)
//
#include <hip/hip_runtime.h>
#include <math.h>

// Problem constants (fixed by the reference file)
//   B=32, H=64, KVH=8, D=128, HID=8192, CL=1024, START_POS=511, padded=512
#define SCALE_ 0.08838834764831845f  // 1/sqrt(128)

// Workspace layout (float offsets). Total 917504 floats = 3.67 MB.
#define OFF_XT   0L        // xT[8192][32]   (aliased as attnT[8192][32] after QKV gemm)
#define OFF_QACC 262144L   // q_acc[8192][32]  (atomic accumulation target)
#define OFF_KACC 524288L   // k_acc[1024][32]
#define OFF_VACC 557056L   // v_acc[1024][32]
#define OFF_QFIN 589824L   // q_fin[32][8192]  (RoPE'd)
#define OFF_KNEW 851968L   // k_new[32][1024]  (RoPE'd)
#define OFF_VNEW 884736L   // v_new[32][1024]

// ---------------------------------------------------------------------------
// K1: transpose x (32 x 8192) -> xT (8192 x 32), LDS-tiled, conflict-free
// ---------------------------------------------------------------------------
__global__ __launch_bounds__(256) void transpose_x(const float* __restrict__ x,
                                                   float* __restrict__ xT)
{
  __shared__ float tile[256 * 33];
  const int t = threadIdx.x;
  const long k0 = (long)blockIdx.x * 256;
#pragma unroll 4
  for (int b = 0; b < 32; ++b)
    tile[t * 33 + b] = x[(long)b * 8192 + k0 + t];   // coalesced read
  __syncthreads();
#pragma unroll 4
  for (int p = 0; p < 32; ++p) {
    int idx = p * 256 + t;                            // 0..8191
    xT[k0 * 32 + idx] = tile[(idx >> 5) * 33 + (idx & 31)];  // coalesced write
  }
}

// ---------------------------------------------------------------------------
// Skinny GEMM core: out[c,b] += sum_k W[c][k] * xT[k][b]   (M=32, split-K)
// Block = 256 thr = 4 waves. lane -> col-pair (128 cols/block), wave -> 8 batches.
// W rows streamed per-lane with float4 (L1 shared across waves);
// xT reads are wave-uniform (1 line/instr).
// ---------------------------------------------------------------------------
static __device__ __forceinline__ void gemm_core(
    const float* __restrict__ W, int colbase, const float* __restrict__ xT,
    float* __restrict__ out, long cs, long bs, int k0)
{
  const int lane = threadIdx.x & 63;
  const int wv   = threadIdx.x >> 6;
  const int b0   = wv * 8;
  const int c    = colbase + lane * 2;
  const float* w0  = W + (long)c * 8192 + k0;
  const float* w1  = w0 + 8192;
  const float* xp0 = xT + (long)k0 * 32 + b0;

  float acc0[8], acc1[8];
#pragma unroll
  for (int i = 0; i < 8; ++i) { acc0[i] = 0.f; acc1[i] = 0.f; }

  for (int k = 0; k < 512; k += 4) {
    float4 wa = *(const float4*)(w0 + k);
    float4 wb = *(const float4*)(w1 + k);
    const float* wav = (const float*)&wa;
    const float* wbv = (const float*)&wb;
    const float* xp  = xp0 + (long)k * 32;
#pragma unroll
    for (int j = 0; j < 4; ++j) {
      float4 xlo = *(const float4*)(xp + j * 32);      // wave-uniform
      float4 xhi = *(const float4*)(xp + j * 32 + 4);  // wave-uniform
      float a = wav[j], g = wbv[j];
      acc0[0] += a * xlo.x;  acc0[1] += a * xlo.y;
      acc0[2] += a * xlo.z;  acc0[3] += a * xlo.w;
      acc0[4] += a * xhi.x;  acc0[5] += a * xhi.y;
      acc0[6] += a * xhi.z;  acc0[7] += a * xhi.w;
      acc1[0] += g * xlo.x;  acc1[1] += g * xlo.y;
      acc1[2] += g * xlo.z;  acc1[3] += g * xlo.w;
      acc1[4] += g * xhi.x;  acc1[5] += g * xhi.y;
      acc1[6] += g * xhi.z;  acc1[7] += g * xhi.w;
    }
  }
#pragma unroll
  for (int i = 0; i < 8; ++i) {
    atomicAdd(out + (long)c * cs       + (long)(b0 + i) * bs, acc0[i]);
    atomicAdd(out + (long)(c + 1) * cs + (long)(b0 + i) * bs, acc1[i]);
  }
}

// K2: fused QKV projection. 1280 blocks = 80 col-blocks x 16 K-splits (5/CU exact).
__global__ __launch_bounds__(256) void gemm_qkv(
    const float* __restrict__ wq, const float* __restrict__ wk,
    const float* __restrict__ wv, const float* __restrict__ xT,
    float* __restrict__ qacc, float* __restrict__ kacc, float* __restrict__ vacc)
{
  const int item = blockIdx.x;
  const int cb = item % 80;        // virtual 10240-col matrix: q | k | v
  const int ks = item / 80;
  const int k0 = ks * 512;
  const float* W; float* out; int colbase;
  if (cb < 64)      { W = wq; out = qacc; colbase = cb * 128; }
  else if (cb < 72) { W = wk; out = kacc; colbase = (cb - 64) * 128; }
  else              { W = wv; out = vacc; colbase = (cb - 72) * 128; }
  gemm_core(W, colbase, xT, out, /*cs=*/32, /*bs=*/1, k0);
}

// K5: output projection. 1024 blocks = 64 col-blocks x 16 K-splits (4/CU exact).
__global__ __launch_bounds__(256) void gemm_wo(
    const float* __restrict__ wo, const float* __restrict__ attnT,
    float* __restrict__ out /* d_out[b][8192] */)
{
  const int item = blockIdx.x;
  const int cb = item & 63;
  const int ks = item >> 6;
  gemm_core(wo, cb * 128, attnT, out, /*cs=*/1, /*bs=*/8192, ks * 512);
}

// ---------------------------------------------------------------------------
// K3: reduce-free finish: apply RoPE to q,k (cos/sin read from rot_mat), copy v.
// tid -> (pair p, batch b=tid&31) so acc reads are fully coalesced.
// ---------------------------------------------------------------------------
__global__ __launch_bounds__(256) void finish_rope(
    const float* __restrict__ qacc, const float* __restrict__ kacc,
    const float* __restrict__ vacc, const float* __restrict__ rot,
    float* __restrict__ qfin, float* __restrict__ knew, float* __restrict__ vnew)
{
  const int tid = blockIdx.x * 256 + threadIdx.x;   // 0..163839
  const int p = tid >> 5;                           // pair index 0..5119
  const int b = tid & 31;
  if (p < 4096) {                                   // q: 4096 pairs
    const int col = p * 2;
    const float e = qacc[(long)col * 32 + b];
    const float o = qacc[(long)(col + 1) * 32 + b];
    const int i = p & 63;                           // d-pair within head
    const float cs = rot[(2 * i) * 128 + 2 * i];
    const float sn = rot[(2 * i + 1) * 128 + 2 * i];
    qfin[(long)b * 8192 + col]     = e * cs + o * sn;
    qfin[(long)b * 8192 + col + 1] = o * cs - e * sn;
  } else if (p < 4608) {                            // k: 512 pairs
    const int idx = p - 4096;
    const int col = idx * 2;
    const float e = kacc[col * 32 + b];
    const float o = kacc[(col + 1) * 32 + b];
    const int i = idx & 63;
    const float cs = rot[(2 * i) * 128 + 2 * i];
    const float sn = rot[(2 * i + 1) * 128 + 2 * i];
    knew[b * 1024 + col]     = e * cs + o * sn;
    knew[b * 1024 + col + 1] = o * cs - e * sn;
  } else {                                          // v: 512 pairs, plain copy
    const int idx = p - 4608;
    const int col = idx * 2;
    vnew[b * 1024 + col]     = vacc[col * 32 + b];
    vnew[b * 1024 + col + 1] = vacc[(col + 1) * 32 + b];
  }
}

// ---------------------------------------------------------------------------
// K4: GQA decode attention, one block per (b, kvh) = 256 blocks (1/CU).
// Phase A: thread-per-position QK^T (q broadcast from LDS).
// Softmax: wave-parallel shfl reduction, 2 rows/wave.
// Phase B: coalesced P@V, output written transposed attnT[col][b].
// Position 511 uses k_new/v_new (cache inputs are never modified).
// ---------------------------------------------------------------------------
__global__ __launch_bounds__(256) void attn_kernel(
    const float* __restrict__ qfin, const float* __restrict__ knew,
    const float* __restrict__ vnew, const float* __restrict__ cache_k,
    const float* __restrict__ cache_v, float* __restrict__ attnT)
{
  __shared__ float q_lds[8 * 128];
  __shared__ float s_lds[8 * 512];
  __shared__ float inv_lds[8];

  const int b = blockIdx.x >> 3;
  const int g = blockIdx.x & 7;    // kv head
  const int t = threadIdx.x;

  // stage q[8][128]
  {
    const float* qsrc = qfin + (long)b * 8192 + g * 1024;
    *(float4*)&q_lds[t * 4] = *(const float4*)&qsrc[t * 4];
  }
  __syncthreads();

  // ---- Phase A: scores ----
  {
    const int posA = t;            // 0..255
    const int posB = t + 256;      // 256..511
    const float* ka = cache_k + (((long)b * 8 + g) * 1024 + posA) * 128;
    const float* kb = (posB == 511)
                    ? (knew + (long)b * 1024 + g * 128)
                    : cache_k + (((long)b * 8 + g) * 1024 + posB) * 128;
    float accA[8], accB[8];
#pragma unroll
    for (int r = 0; r < 8; ++r) { accA[r] = 0.f; accB[r] = 0.f; }
    const float4* q4p = (const float4*)q_lds;
    for (int dv = 0; dv < 32; ++dv) {
      float4 Ka = ((const float4*)ka)[dv];
      float4 Kb = ((const float4*)kb)[dv];
#pragma unroll
      for (int r = 0; r < 8; ++r) {
        float4 q4 = q4p[r * 32 + dv];                 // LDS broadcast
        accA[r] += q4.x * Ka.x + q4.y * Ka.y + q4.z * Ka.z + q4.w * Ka.w;
        accB[r] += q4.x * Kb.x + q4.y * Kb.y + q4.z * Kb.z + q4.w * Kb.w;
      }
    }
#pragma unroll
    for (int r = 0; r < 8; ++r) {
      s_lds[r * 512 + posA] = accA[r] * SCALE_;
      s_lds[r * 512 + posB] = accB[r] * SCALE_;
    }
  }
  __syncthreads();

  // ---- Softmax: wave w handles rows 2w, 2w+1 ----
  {
    const int w = t >> 6, lane = t & 63;
#pragma unroll
    for (int rr = 0; rr < 2; ++rr) {
      const int r = w * 2 + rr;
      float* row = &s_lds[r * 512];
      float4 a = *(float4*)&row[lane * 8];
      float4 c = *(float4*)&row[lane * 8 + 4];
      float m = fmaxf(fmaxf(fmaxf(a.x, a.y), fmaxf(a.z, a.w)),
                      fmaxf(fmaxf(c.x, c.y), fmaxf(c.z, c.w)));
#pragma unroll
      for (int off = 1; off < 64; off <<= 1)
        m = fmaxf(m, __shfl_xor(m, off));
      a.x = __expf(a.x - m); a.y = __expf(a.y - m);
      a.z = __expf(a.z - m); a.w = __expf(a.w - m);
      c.x = __expf(c.x - m); c.y = __expf(c.y - m);
      c.z = __expf(c.z - m); c.w = __expf(c.w - m);
      float ssum = a.x + a.y + a.z + a.w + c.x + c.y + c.z + c.w;
#pragma unroll
      for (int off = 1; off < 64; off <<= 1)
        ssum += __shfl_xor(ssum, off);
      *(float4*)&row[lane * 8]     = a;
      *(float4*)&row[lane * 8 + 4] = c;
      if (lane == 0) inv_lds[r] = 1.0f / ssum;
    }
  }
  __syncthreads();

  // ---- Phase B: out[r][d] = sum_s p[r][s] * V[s][d], coalesced V rows ----
  {
    const int r  = t >> 5;
    const int dl = (t & 31) * 4;
    const float* vbase = cache_v + ((long)b * 8 + g) * 1024 * 128 + dl;
    const float* prow  = &s_lds[r * 512];
    float4 acc = {0.f, 0.f, 0.f, 0.f};
    for (int s = 0; s < 508; s += 4) {
      float4 p4 = *(const float4*)&prow[s];
      const float* pv = (const float*)&p4;
#pragma unroll
      for (int ss = 0; ss < 4; ++ss) {
        float4 v4 = *(const float4*)&vbase[(long)(s + ss) * 128];
        acc.x += pv[ss] * v4.x; acc.y += pv[ss] * v4.y;
        acc.z += pv[ss] * v4.z; acc.w += pv[ss] * v4.w;
      }
    }
    {   // tail: 508,509,510 from cache, 511 from v_new
      float4 p4 = *(const float4*)&prow[508];
      const float* pv = (const float*)&p4;
      float4 v4;
      v4 = *(const float4*)&vbase[508L * 128];
      acc.x += pv[0] * v4.x; acc.y += pv[0] * v4.y; acc.z += pv[0] * v4.z; acc.w += pv[0] * v4.w;
      v4 = *(const float4*)&vbase[509L * 128];
      acc.x += pv[1] * v4.x; acc.y += pv[1] * v4.y; acc.z += pv[1] * v4.z; acc.w += pv[1] * v4.w;
      v4 = *(const float4*)&vbase[510L * 128];
      acc.x += pv[2] * v4.x; acc.y += pv[2] * v4.y; acc.z += pv[2] * v4.z; acc.w += pv[2] * v4.w;
      const float* vn = vnew + (long)b * 1024 + g * 128 + dl;
      v4 = *(const float4*)vn;
      acc.x += pv[3] * v4.x; acc.y += pv[3] * v4.y; acc.z += pv[3] * v4.z; acc.w += pv[3] * v4.w;
    }
    const float inv = inv_lds[r];
    const long col = ((long)g * 8 + r) * 128 + dl;    // h*128 + d
    attnT[col * 32 + b]       = acc.x * inv;
    attnT[(col + 1) * 32 + b] = acc.y * inv;
    attnT[(col + 2) * 32 + b] = acc.z * inv;
    attnT[(col + 3) * 32 + b] = acc.w * inv;
  }
}

// ---------------------------------------------------------------------------
extern "C" void kernel_launch(void* const* d_in, const int* in_sizes, int n_in,
                              void* d_out, int out_size, void* d_ws, size_t ws_size,
                              hipStream_t stream)
{
  (void)in_sizes; (void)n_in; (void)out_size; (void)ws_size;
  const float* x   = (const float*)d_in[0];
  const float* wq  = (const float*)d_in[1];
  const float* wk  = (const float*)d_in[2];
  const float* wv  = (const float*)d_in[3];
  const float* wo  = (const float*)d_in[4];
  const float* ck  = (const float*)d_in[5];
  const float* cv  = (const float*)d_in[6];
  const float* rot = (const float*)d_in[7];
  // d_in[8] = start_pos (fixed at 511 for this problem instance)

  float* out  = (float*)d_out;
  float* ws   = (float*)d_ws;
  float* xT   = ws + OFF_XT;      // doubles as attnT after the QKV gemm
  float* qacc = ws + OFF_QACC;
  float* kacc = ws + OFF_KACC;
  float* vacc = ws + OFF_VACC;
  float* qfin = ws + OFF_QFIN;
  float* knew = ws + OFF_KNEW;
  float* vnew = ws + OFF_VNEW;

  // zero the atomic-accumulation targets (ws/d_out are poisoned 0xAA)
  hipMemsetAsync(qacc, 0, (262144 + 32768 + 32768) * sizeof(float), stream);
  hipMemsetAsync(out, 0, 262144 * sizeof(float), stream);

  transpose_x<<<32, 256, 0, stream>>>(x, xT);
  gemm_qkv<<<1280, 256, 0, stream>>>(wq, wk, wv, xT, qacc, kacc, vacc);
  finish_rope<<<640, 256, 0, stream>>>(qacc, kacc, vacc, rot, qfin, knew, vnew);
  attn_kernel<<<256, 256, 0, stream>>>(qfin, knew, vnew, ck, cv, xT /*attnT*/);
  gemm_wo<<<1024, 256, 0, stream>>>(wo, xT /*attnT*/, out);
}